// Round 12
// baseline (1795.662 us; speedup 1.0000x reference)
//
#include <hip/hip_runtime.h>
#include <cstdint>
#include <cstddef>

#define DIM    1024
#define NH     16
#define HD     64
#define CHUNK_ 16
#define SEQ    4096
#define BATCH  4
#define NROWS  (BATCH * SEQ)       // 16384
#define NCHUNK (SEQ / CHUNK_)      // 256
#define SEG    64
#define NSEG   (SEQ / SEG)         // 64

using bf16x8 = __attribute__((ext_vector_type(8))) short;
using f32x4  = __attribute__((ext_vector_type(4))) float;
typedef union { bf16x8 v; uint32_t u[4]; } B8;

#define MFMA16(a, b, c) __builtin_amdgcn_mfma_f32_16x16x32_bf16((a), (b), (c), 0, 0, 0)

__device__ __forceinline__ ushort f2bf(float f) {
    uint32_t u = __float_as_uint(f);
    u += 0x7FFFu + ((u >> 16) & 1u);      // RTNE
    return (ushort)(u >> 16);
}
__device__ __forceinline__ uint32_t pack2(float a, float b) {
    return (uint32_t)f2bf(a) | ((uint32_t)f2bf(b) << 16);
}
__device__ __forceinline__ float b2f(ushort u) {
    return __uint_as_float(((uint32_t)u) << 16);
}
__device__ __forceinline__ float dot4(const float4 a, const float4 b) {
    return a.x*b.x + a.y*b.y + a.z*b.z + a.w*b.w;
}

// DPP row-of-16 rotate reduction (VALU pipe) — verified R10
template <int N>
__device__ __forceinline__ float ror16(float x) {
    return __int_as_float(__builtin_amdgcn_update_dpp(
        0, __float_as_int(x), 0x120 + N, 0xF, 0xF, true));   // ROW_ROR:N
}
__device__ __forceinline__ float dppsum16(float x) {
    x += ror16<1>(x); x += ror16<2>(x);
    x += ror16<4>(x); x += ror16<8>(x);
    return x;
}

// single-wave "barrier": compiler-only fence (verified rounds 6-11)
#define SYNC() do { asm volatile("" ::: "memory");          \
                    __builtin_amdgcn_wave_barrier();        \
                    __builtin_amdgcn_sched_barrier(0); } while (0)

__device__ __forceinline__ void gl_lds16(const void* g, void* l) {
    __builtin_amdgcn_global_load_lds(
        (const __attribute__((address_space(1))) void*)g,
        (__attribute__((address_space(3))) void*)l, 16, 0, 0);
}

// ---------------------------------------------------------------------------
// fp32 -> bf16 converters
// ---------------------------------------------------------------------------
__global__ __launch_bounds__(256)
void f2b_kernel(const float* __restrict__ in, ushort* __restrict__ out, int n8)
{
    int i = blockIdx.x * 256 + threadIdx.x;
    const int stride = gridDim.x * 256;
    for (; i < n8; i += stride) {
        float4 a = *(const float4*)&in[(size_t)i * 8];
        float4 b = *(const float4*)&in[(size_t)i * 8 + 4];
        uint4 u;
        u.x = pack2(a.x, a.y); u.y = pack2(a.z, a.w);
        u.z = pack2(b.x, b.y); u.w = pack2(b.z, b.w);
        *(uint4*)&out[(size_t)i * 8] = u;
    }
}

// all 5 weight matrices in one dispatch (dst contiguous)
__global__ __launch_bounds__(256)
void f2b5_kernel(const float* __restrict__ w0, const float* __restrict__ w1,
                 const float* __restrict__ w2, const float* __restrict__ w3,
                 const float* __restrict__ w4, ushort* __restrict__ out)
{
    const int W8 = DIM * DIM / 8;
    const int w  = blockIdx.x >> 7;           // 128 blocks per weight
    const float* src = (w == 0) ? w0 : (w == 1) ? w1 : (w == 2) ? w2
                     : (w == 3) ? w3 : w4;
    ushort* dst = out + (size_t)w * DIM * DIM;
    for (int i = (blockIdx.x & 127) * 256 + threadIdx.x; i < W8; i += 128 * 256) {
        float4 a = *(const float4*)&src[(size_t)i * 8];
        float4 b = *(const float4*)&src[(size_t)i * 8 + 4];
        uint4 u;
        u.x = pack2(a.x, a.y); u.y = pack2(a.z, a.w);
        u.z = pack2(b.x, b.y); u.w = pack2(b.z, b.w);
        *(uint4*)&dst[(size_t)i * 8] = u;
    }
}

// ---------------------------------------------------------------------------
// m97-style bf16 GEMM (NT) — verified R11
// ---------------------------------------------------------------------------
#define GEMM_LDS_BODY(EPILOG)                                                  \
    __shared__ ushort As[128][64];                                             \
    __shared__ ushort Bs[128][64];                                             \
    const int tid  = threadIdx.x, wave = tid >> 6, lane = tid & 63;            \
    const int m0   = blockIdx.y * 128, n0 = blockIdx.x * 128;                  \
    const int lo   = lane & 15, kg = lane >> 4;                                \
    const int wm   = (wave >> 1) * 64, wn = (wave & 1) * 64;                   \
    const int rin  = lane >> 3, sl = lane & 7;                                 \
    const int sb   = 32 * wave;                                                \
    f32x4 acc[4][4];                                                           \
    _Pragma("unroll")                                                          \
    for (int i = 0; i < 4; ++i)                                                \
        _Pragma("unroll")                                                      \
        for (int j = 0; j < 4; ++j) acc[i][j] = (f32x4){0.f, 0.f, 0.f, 0.f};   \
    const int swz = lo & 7;                                                    \
    for (int kt = 0; kt < K; kt += 64) {                                       \
        __syncthreads();                                                       \
        _Pragma("unroll")                                                      \
        for (int i = 0; i < 4; ++i) {                                          \
            const int row = sb + 8 * i + rin;                                  \
            const int gs  = sl ^ (row & 7);                                    \
            gl_lds16(A + (size_t)(m0 + row) * K + kt + gs * 8,                 \
                     &As[sb + 8 * i][0]);                                      \
            gl_lds16(B + (size_t)(n0 + row) * K + kt + gs * 8,                 \
                     &Bs[sb + 8 * i][0]);                                      \
        }                                                                      \
        __syncthreads();                                                       \
        bf16x8 af[2][4], bfr[2][4];                                            \
        _Pragma("unroll")                                                      \
        for (int kk = 0; kk < 2; ++kk)                                         \
            _Pragma("unroll")                                                  \
            for (int m = 0; m < 4; ++m) {                                      \
                const int s = (kk * 4 + kg) ^ swz;                             \
                af[kk][m]  = *(const bf16x8*)&As[wm + m * 16 + lo][s * 8];     \
                bfr[kk][m] = *(const bf16x8*)&Bs[wn + m * 16 + lo][s * 8];     \
            }                                                                  \
        _Pragma("unroll")                                                      \
        for (int kk = 0; kk < 2; ++kk)                                         \
            _Pragma("unroll")                                                  \
            for (int mt = 0; mt < 4; ++mt)                                     \
                _Pragma("unroll")                                              \
                for (int nt = 0; nt < 4; ++nt)                                 \
                    acc[mt][nt] = MFMA16(af[kk][mt], bfr[kk][nt], acc[mt][nt]);\
    }                                                                          \
    const int col = lane & 15, r4 = (lane >> 4) * 4;                           \
    _Pragma("unroll")                                                          \
    for (int mt = 0; mt < 4; ++mt)                                             \
        _Pragma("unroll")                                                      \
        for (int nt = 0; nt < 4; ++nt)                                         \
            _Pragma("unroll")                                                  \
            for (int j = 0; j < 4; ++j) {                                      \
                size_t idx = (size_t)(m0 + wm + mt * 16 + r4 + j) * DIM +      \
                             n0 + wn + nt * 16 + col;                          \
                EPILOG;                                                        \
            }

__global__ __launch_bounds__(256)
void gemm_lds_b16o(const ushort* __restrict__ A, const ushort* __restrict__ B,
                   ushort* __restrict__ C, int K)
{
    GEMM_LDS_BODY(C[idx] = f2bf(acc[mt][nt][j]))
}

__global__ __launch_bounds__(256)
void gemm_lds_f32o(const ushort* __restrict__ A, const ushort* __restrict__ B,
                   float* __restrict__ C, int K)
{
    GEMM_LDS_BODY(C[idx] = acc[mt][nt][j])
}

// ---------------------------------------------------------------------------
// lr kernel (exact fp32)
// ---------------------------------------------------------------------------
__global__ __launch_bounds__(256)
void lr_kernel(const float* __restrict__ hs, const float* __restrict__ Wlr,
               float* __restrict__ LR)
{
    __shared__ float row[DIM];
    const int r = blockIdx.x;
    const int t = threadIdx.x;
    *(float4*)&row[t * 4] = *(const float4*)&hs[(size_t)r * DIM + t * 4];
    __syncthreads();

    const int o = t >> 3;
    const int p = t & 7;
    const float* w = Wlr + (size_t)o * DIM + p * 128;
    const float* x = row + p * 128;
    float acc = 0.f;
#pragma unroll
    for (int i = 0; i < 32; ++i) {
        float4 xv = *(const float4*)(x + i * 4);
        float4 wv = *(const float4*)(w + i * 4);
        acc += dot4(xv, wv);
    }
    acc += __shfl_xor(acc, 1);
    acc += __shfl_xor(acc, 2);
    acc += __shfl_xor(acc, 4);
    if (p == 0) {
        float xx = acc + 0.001f;
        LR[(size_t)r * 32 + o] = (xx > 20.f) ? xx : log1pf(expf(xx));
    }
}

// ---------------------------------------------------------------------------
// halo save (bf16 — verified R11)
// ---------------------------------------------------------------------------
__global__ __launch_bounds__(256)
void halo_save(const ushort* __restrict__ Q, const ushort* __restrict__ K,
               const ushort* __restrict__ V, ushort* __restrict__ HALO)
{
    int idx = blockIdx.x;
    int tn  = idx / (BATCH * (NSEG - 1) * 3);
    int rem = idx - tn * (BATCH * (NSEG - 1) * 3);
    int b   = rem / ((NSEG - 1) * 3);
    int rem2= rem - b * ((NSEG - 1) * 3);
    int s   = rem2 / 3 + 1;
    int j   = rem2 - (s - 1) * 3;

    const ushort* buf = (tn == 0) ? Q : ((tn == 1) ? K : V);
    size_t src = ((size_t)(b * SEQ + s * SEG - 3 + j)) * DIM + threadIdx.x * 4;
    size_t dst = ((size_t)((tn * BATCH + b) * NSEG + s) * 3 + j) * DIM + threadIdx.x * 4;
    *(uint2*)&HALO[dst] = *(const uint2*)&buf[src];
}

// ---------------------------------------------------------------------------
// conv in-place (bf16 buffers, fp32 math — verified R11)
// ---------------------------------------------------------------------------
__global__ __launch_bounds__(256)
void conv_inplace(ushort* __restrict__ Q, ushort* __restrict__ K,
                  ushort* __restrict__ V, const ushort* __restrict__ HALO,
                  const float* __restrict__ cq, const float* __restrict__ ck,
                  const float* __restrict__ cv)
{
    const int wid  = (blockIdx.x << 2) + (threadIdx.x >> 6);
    const int lane = threadIdx.x & 63;
    const int tn   = wid >> 12;
    const int rem  = wid & 4095;
    const int b    = rem >> 10;
    const int rem2 = rem & 1023;
    const int h    = rem2 >> 6;
    const int s    = rem2 & 63;
    const int c    = (h << 6) + lane;

    ushort* buf = (tn == 0) ? Q : ((tn == 1) ? K : V);
    const float* cw = (tn == 0) ? cq : ((tn == 1) ? ck : cv);
    float4 w4 = *(const float4*)(cw + (c << 2));

    float xm3 = 0.f, xm2 = 0.f, xm1 = 0.f;
    if (s > 0) {
        size_t hb = ((size_t)((tn * BATCH + b) * NSEG + s) * 3) * DIM + c;
        xm3 = b2f(HALO[hb]);
        xm2 = b2f(HALO[hb + DIM]);
        xm1 = b2f(HALO[hb + 2 * DIM]);
    }

    size_t base = ((size_t)(b * SEQ + s * SEG)) * DIM + c;
    float x_next = b2f(buf[base]);
#pragma unroll 4
    for (int i = 0; i < SEG; ++i) {
        float x = x_next;
        if (i < SEG - 1) x_next = b2f(buf[base + (size_t)(i + 1) * DIM]);
        float y = xm3 * w4.x + xm2 * w4.y + xm1 * w4.z + x * w4.w + x;
        y = y / (1.f + __expf(-y));
        if (tn < 2) {
            float n2 = y * y;
#pragma unroll
            for (int m = 1; m < 64; m <<= 1) n2 += __shfl_xor(n2, m);
            y *= rsqrtf(n2);
        }
        buf[base + (size_t)i * DIM] = f2bf(y);
        xm3 = xm2; xm2 = xm1; xm1 = x;
    }
}

// ---------------------------------------------------------------------------
// MFMA scan: W state ENTIRELY IN REGISTERS.
// State layout: lane (lo,g) reg r of w[n] = W^T[d=16n+4g+r][D=lo]
// (produced naturally by TRANSPOSED updates: MFMA(X=KT/VT-frag, Y=P-frag)).
// W frags for logits/scores built via 16 pipelined shfls (select n by g&2
// AFTER the shfl). No WiA/WoA/KH LDS arrays; no scalar write-backs.
// kh^T from cKT = MFMA(aKA, fWi) (operand swap, reused as it=0 score).
// ---------------------------------------------------------------------------
#define BUILD_WFRAG(W, F0, F1) do {                                           \
    uint32_t pa0 = pack2(W[0][0], W[0][1]), pb0 = pack2(W[0][2], W[0][3]);    \
    uint32_t pa1 = pack2(W[1][0], W[1][1]), pb1 = pack2(W[1][2], W[1][3]);    \
    uint32_t pa2 = pack2(W[2][0], W[2][1]), pb2 = pack2(W[2][2], W[2][3]);    \
    uint32_t pa3 = pack2(W[3][0], W[3][1]), pb3 = pack2(W[3][2], W[3][3]);    \
    uint32_t a0L0 = (uint32_t)__shfl((int)pa0, Lw0);                          \
    uint32_t a1L0 = (uint32_t)__shfl((int)pa1, Lw0);                          \
    uint32_t a2L0 = (uint32_t)__shfl((int)pa2, Lw0);                          \
    uint32_t a3L0 = (uint32_t)__shfl((int)pa3, Lw0);                          \
    uint32_t b0L0 = (uint32_t)__shfl((int)pb0, Lw0);                          \
    uint32_t b1L0 = (uint32_t)__shfl((int)pb1, Lw0);                          \
    uint32_t b2L0 = (uint32_t)__shfl((int)pb2, Lw0);                          \
    uint32_t b3L0 = (uint32_t)__shfl((int)pb3, Lw0);                          \
    uint32_t a0L1 = (uint32_t)__shfl((int)pa0, Lw1);                          \
    uint32_t a1L1 = (uint32_t)__shfl((int)pa1, Lw1);                          \
    uint32_t a2L1 = (uint32_t)__shfl((int)pa2, Lw1);                          \
    uint32_t a3L1 = (uint32_t)__shfl((int)pa3, Lw1);                          \
    uint32_t b0L1 = (uint32_t)__shfl((int)pb0, Lw1);                          \
    uint32_t b1L1 = (uint32_t)__shfl((int)pb1, Lw1);                          \
    uint32_t b2L1 = (uint32_t)__shfl((int)pb2, Lw1);                          \
    uint32_t b3L1 = (uint32_t)__shfl((int)pb3, Lw1);                          \
    B8 f0_, f1_;                                                              \
    f0_.u[0] = selg ? a1L0 : a0L0;  f0_.u[1] = selg ? b1L0 : b0L0;            \
    f0_.u[2] = selg ? a1L1 : a0L1;  f0_.u[3] = selg ? b1L1 : b0L1;            \
    f1_.u[0] = selg ? a3L0 : a2L0;  f1_.u[1] = selg ? b3L0 : b2L0;            \
    f1_.u[2] = selg ? a3L1 : a2L1;  f1_.u[3] = selg ? b3L1 : b2L1;            \
    F0 = f0_.v; F1 = f1_.v;                                                   \
} while (0)

__global__ __launch_bounds__(64)
void scan_kernel(const ushort* QP, const ushort* __restrict__ KP,
                 const ushort* __restrict__ VP, const float* __restrict__ LRb,
                 const float* __restrict__ GATE,
                 const float* __restrict__ Wi0, const float* __restrict__ Wo0,
                 const float* __restrict__ lng, const float* __restrict__ lnb,
                 ushort* OB)
{
    const int bh = blockIdx.x, b = bh >> 4, h = bh & 15;
    const int t  = threadIdx.x, lo = t & 15, g = t >> 4;

    __shared__ ushort KA2[2][16][72], QA2[2][16][72], VA2[2][16][72];
    __shared__ float  sG2[2][16][68];
    __shared__ ushort KT2[2][64][24];
    __shared__ ushort VT2[2][64][40];            // [d][V^T | Wo^T(16-19) | 0]
    __shared__ ushort QKT[16][32];               // [q][qk | q_h | 0]

    for (int i = t; i < 2 * 64 * 24; i += 64) ((ushort*)KT2)[i] = 0;
    for (int i = t; i < 2 * 64 * 40; i += 64) ((ushort*)VT2)[i] = 0;
    for (int i = t; i < 16 * 32; i += 64) ((ushort*)QKT)[i] = 0;

    // ---- W state in registers (transposed layout) ----
    f32x4 wiC[4], woC[4];
#pragma unroll
    for (int n = 0; n < 4; ++n)
#pragma unroll
        for (int r = 0; r < 4; ++r) {
            const int d = 16 * n + 4 * g + r;
            float wi = 0.f, wo = 0.f;
            if (lo < 4) {
                wi = Wi0[((size_t)lo * NH + h) * HD + d];
                wo = Wo0[((size_t)lo * NH + h) * HD + d];
            }
            wiC[n][r] = wi; woC[n][r] = wo;
        }
    if (lo < 4) {
#pragma unroll
        for (int n = 0; n < 4; ++n)
#pragma unroll
            for (int r = 0; r < 4; ++r)
                VT2[0][16 * n + 4 * g + r][16 + lo] = f2bf(woC[n][r]);
    }
    SYNC();

    float lnGr[4], lnBr[4];
#pragma unroll
    for (int n = 0; n < 4; ++n) { lnGr[n] = lng[16 * n + lo]; lnBr[n] = lnb[16 * n + lo]; }

    const int rowb = b * SEQ;
    const ushort* QPh = QP + h * 64;
    const ushort* KPh = KP + h * 64;
    const ushort* VPh = VP + h * 64;
    const float*  GPh = GATE + h * 64;
    ushort*       OBh = OB + h * 64;

    uint2 pq[4], pk[4], pv[4];
    float4 pg[4];
    float plr_q, plr_i, plr_o;
    {
#pragma unroll
        for (int i = 0; i < 4; ++i) {
            size_t go = (size_t)(rowb + i * 4 + g) * DIM + 4 * lo;
            pq[i] = *(const uint2*)&QPh[go];
            pk[i] = *(const uint2*)&KPh[go];
            pv[i] = *(const uint2*)&VPh[go];
            pg[i] = *(const float4*)&GPh[go];
        }
        plr_q = LRb[(size_t)(rowb + lo) * 32 + h * 2 + 1];
        plr_i = LRb[(size_t)rowb * 32 + h * 2];
        plr_o = LRb[(size_t)rowb * 32 + h * 2 + 1];
    }

    auto STAGE = [&](int nb) {
#pragma unroll
        for (int i = 0; i < 4; ++i) {
            const int row = i * 4 + g;
            *(float4*)&sG2[nb][row][4 * lo] = pg[i];
            *(uint2*)&QA2[nb][row][4 * lo] = pq[i];
            *(uint2*)&KA2[nb][row][4 * lo] = pk[i];
            *(uint2*)&VA2[nb][row][4 * lo] = pv[i];
            uint2 uk = pk[i], uv = pv[i];
            KT2[nb][4 * lo + 0][row] = (ushort)(uk.x & 0xFFFF);
            KT2[nb][4 * lo + 1][row] = (ushort)(uk.x >> 16);
            KT2[nb][4 * lo + 2][row] = (ushort)(uk.y & 0xFFFF);
            KT2[nb][4 * lo + 3][row] = (ushort)(uk.y >> 16);
            VT2[nb][4 * lo + 0][row] = (ushort)(uv.x & 0xFFFF);
            VT2[nb][4 * lo + 1][row] = (ushort)(uv.x >> 16);
            VT2[nb][4 * lo + 2][row] = (ushort)(uv.y & 0xFFFF);
            VT2[nb][4 * lo + 3][row] = (ushort)(uv.y >> 16);
        }
    };

    STAGE(0);
    SYNC();

    const f32x4 z4 = (f32x4){0.f, 0.f, 0.f, 0.f};
    const uint32_t pmsk = (g < 2) ? 0xFFFFFFFFu : 0u;   // zero k-slices 16..31
    const int L0 = (lo + 32 * g) & 63, L1 = (L0 + 16) & 63;
    const int Lw0 = lo + 32 * (g & 1), Lw1 = Lw0 + 16;  // W-frag source lanes
    const int selg = g & 2;

    bf16x8 fWi0, fWi1, fWo0, fWo1;
    BUILD_WFRAG(wiC, fWi0, fWi1);

    for (int c = 0; c < NCHUNK; ++c) {
        const int rb  = rowb + c * CHUNK_;
        const int cur = c & 1, nxt = cur ^ 1;
        ushort (*KAc)[72] = KA2[cur];
        ushort (*QAc)[72] = QA2[cur];
        ushort (*VAc)[72] = VA2[cur];
        float  (*sGc)[68] = sG2[cur];
        ushort (*KTc)[24] = KT2[cur];
        ushort (*VTc)[40] = VT2[cur];

        const float lr1v   = plr_q;
        const float lr_in  = plr_i;
        const float lr_out = plr_o;

        // ---- issue prefetch for chunk c+1 ----
        if (c + 1 < NCHUNK) {
            const int rb2 = rb + CHUNK_;
#pragma unroll
            for (int i = 0; i < 4; ++i) {
                size_t go = (size_t)(rb2 + i * 4 + g) * DIM + 4 * lo;
                pq[i] = *(const uint2*)&QPh[go];
                pk[i] = *(const uint2*)&KPh[go];
                pv[i] = *(const uint2*)&VPh[go];
                pg[i] = *(const float4*)&GPh[go];
            }
            plr_q = LRb[(size_t)(rb2 + lo) * 32 + h * 2 + 1];
            plr_i = LRb[(size_t)rb2 * 32 + h * 2];
            plr_o = LRb[(size_t)rb2 * 32 + h * 2 + 1];
        }

        // ---- phase A: logits (both layouts), softmaxes, qk, bounce ----
        bf16x8 aKA0 = *(const bf16x8*)&KAc[lo][g * 8];
        bf16x8 aKA1 = *(const bf16x8*)&KAc[lo][g * 8 + 32];
        bf16x8 aQA0 = *(const bf16x8*)&QAc[lo][g * 8];
        bf16x8 aQA1 = *(const bf16x8*)&QAc[lo][g * 8 + 32];
        bf16x8 aVA0 = *(const bf16x8*)&VAc[lo][g * 8];
        bf16x8 aVA1 = *(const bf16x8*)&VAc[lo][g * 8 + 32];

        f32x4 cK = MFMA16(fWi0, aKA0, z4);  cK = MFMA16(fWi1, aKA1, cK);
        f32x4 cQ = MFMA16(fWi0, aQA0, z4);  cQ = MFMA16(fWi1, aQA1, cQ);
        f32x4 cKT = MFMA16(aKA0, fWi0, z4); cKT = MFMA16(aKA1, fWi1, cKT);

        // register-local softmax over D (valid on g==0 lanes)
        float mK = fmaxf(fmaxf(cK[0], cK[1]), fmaxf(cK[2], cK[3]));
        float ek0 = __expf(cK[0] - mK), ek1 = __expf(cK[1] - mK);
        float ek2 = __expf(cK[2] - mK), ek3 = __expf(cK[3] - mK);
        float ivk = lr1v / (ek0 + ek1 + ek2 + ek3);
        float kh0 = ek0 * ivk, kh1 = ek1 * ivk, kh2 = ek2 * ivk, kh3 = ek3 * ivk;

        float mQ = fmaxf(fmaxf(cQ[0], cQ[1]), fmaxf(cQ[2], cQ[3]));
        float eq0 = __expf(cQ[0] - mQ), eq1 = __expf(cQ[1] - mQ);
        float eq2 = __expf(cQ[2] - mQ), eq3 = __expf(cQ[3] - mQ);
        float ivq = 1.f / (eq0 + eq1 + eq2 + eq3);
        float qh0 = eq0 * ivq, qh1 = eq1 * ivq, qh2 = eq2 * ivq, qh3 = eq3 * ivq;

        // cross-lane softmax over D on cKT -> kh^T[l=4g+r][D=lo]
        float khT[4];
#pragma unroll
        for (int r = 0; r < 4; ++r) {
            float v = cKT[r];
            float m = fmaxf(v, __shfl_xor(v, 1));
            m = fmaxf(m, __shfl_xor(m, 2));
            float e = __expf(v - m);
            float s = e + __shfl_xor(e, 1);
            s += __shfl_xor(s, 2);
            khT[r] = e / s * __shfl(lr1v, 4 * g + r);
        }
        uint32_t kpkA = pack2(khT[0], khT[1]);
        uint32_t kpkB = pack2(khT[2], khT[3]);
        B8 Ykh;
        Ykh.u[0] = (uint32_t)__shfl((int)kpkA, L0) & pmsk;
        Ykh.u[1] = (uint32_t)__shfl((int)kpkB, L0) & pmsk;
        Ykh.u[2] = (uint32_t)__shfl((int)kpkA, L1) & pmsk;
        Ykh.u[3] = (uint32_t)__shfl((int)kpkB, L1) & pmsk;

        // M3: qk = q_h @ k_h^T (pure-register)
        B8 aQh, bKh;
        aQh.u[0] = aQh.u[1] = aQh.u[2] = aQh.u[3] = 0;
        bKh.u[0] = bKh.u[1] = bKh.u[2] = bKh.u[3] = 0;
        if (g == 0) {
            aQh.u[0] = pack2(qh0, qh1); aQh.u[1] = pack2(qh2, qh3);
            bKh.u[0] = pack2(kh0, kh1); bKh.u[1] = pack2(kh2, kh3);
        }
        f32x4 cQK = MFMA16(aQh.v, bKh.v, z4);

#pragma unroll
        for (int r = 0; r < 4; ++r) {
            const int q = 4 * g + r;
            QKT[q][lo] = (lo <= q) ? f2bf(cQK[r]) : (ushort)0;
        }
        if (g == 0) {
            QKT[lo][16] = f2bf(qh0); QKT[lo][17] = f2bf(qh1);
            QKT[lo][18] = f2bf(qh2); QKT[lo][19] = f2bf(qh3);
        }
        SYNC();

        // ---- phase B: M4 o, LN + gate + store, update1 (transposed) ----
        bf16x8 aO = *(const bf16x8*)&QKT[lo][g * 8];
        bf16x8 vfr[4], kfr[4];
#pragma unroll
        for (int n = 0; n < 4; ++n) {
            vfr[n] = *(const bf16x8*)&VTc[16 * n + lo][g * 8];
            kfr[n] = *(const bf16x8*)&KTc[16 * n + lo][g * 8];
        }
        f32x4 oA[4];
#pragma unroll
        for (int n = 0; n < 4; ++n)
            oA[n] = MFMA16(aO, vfr[n], z4);
#pragma unroll
        for (int r = 0; r < 4; ++r) {
            float s1 = oA[0][r] + oA[1][r] + oA[2][r] + oA[3][r];
            float s2 = oA[0][r] * oA[0][r] + oA[1][r] * oA[1][r] +
                       oA[2][r] * oA[2][r] + oA[3][r] * oA[3][r];
            s1 = dppsum16(s1); s2 = dppsum16(s2);
            float mu = s1 * (1.f / 64.f);
            float rstd = rsqrtf(s2 * (1.f / 64.f) - mu * mu + 1e-5f);
            const int q = 4 * g + r;
#pragma unroll
            for (int n = 0; n < 4; ++n) {
                float val = (oA[n][r] - mu) * rstd * lnGr[n] + lnBr[n];
                val *= sGc[q][16 * n + lo];
                OBh[(size_t)(rb + q) * DIM + 16 * n + lo] = f2bf(val);
            }
        }
        // update1: Wo^T += V^T @ kh^T  (X = VT frag, Y = kh^T frag)
#pragma unroll
        for (int n = 0; n < 4; ++n)
            woC[n] = MFMA16(vfr[n], Ykh.v, woC[n]);
        BUILD_WFRAG(woC, fWo0, fWo1);

        // ---- phases C,D: inner TTT (transposed scores + updates) ----
#pragma unroll
        for (int it = 0; it < 2; ++it) {
            f32x4 s0T;
            if (it == 0) {
                s0T = cKT;                     // == MFMA(aKA, fWi) ✓ reuse
            } else {
                s0T = MFMA16(aKA0, fWi0, z4);
                s0T = MFMA16(aKA1, fWi1, s0T);
            }
            f32x4 s1T = MFMA16(aVA0, fWo0, z4);
            s1T = MFMA16(aVA1, fWo1, s1T);

            float x0[4], x1[4];
#pragma unroll
            for (int r = 0; r < 4; ++r) {
                x0[r] = s0T[r] * 0.125f;
                x1[r] = s1T[r] * 0.125f;
            }
            float m0 = fmaxf(fmaxf(x0[0], x0[1]), fmaxf(x0[2], x0[3]));
            float m1 = fmaxf(fmaxf(x1[0], x1[1]), fmaxf(x1[2], x1[3]));
            m0 = fmaxf(m0, __shfl_xor(m0, 16)); m0 = fmaxf(m0, __shfl_xor(m0, 32));
            m1 = fmaxf(m1, __shfl_xor(m1, 16)); m1 = fmaxf(m1, __shfl_xor(m1, 32));
            float e0[4], e1[4];
#pragma unroll
            for (int r = 0; r < 4; ++r) {
                e0[r] = __expf(x0[r] - m0);
                e1[r] = __expf(x1[r] - m1);
            }
            float su0 = e0[0] + e0[1] + e0[2] + e0[3];
            float su1 = e1[0] + e1[1] + e1[2] + e1[3];
            su0 += __shfl_xor(su0, 16); su0 += __shfl_xor(su0, 32);
            su1 += __shfl_xor(su1, 16); su1 += __shfl_xor(su1, 32);
            const float w0 = lr_out / su0;
            const float w1 = lr_in / su1;

            uint32_t p00 = pack2(e0[0] * w0, e0[1] * w0);
            uint32_t p01 = pack2(e0[2] * w0, e0[3] * w0);
            uint32_t p10 = pack2(e1[0] * w1, e1[1] * w1);
            uint32_t p11 = pack2(e1[2] * w1, e1[3] * w1);
            B8 aP0, aP1;
            aP0.u[0] = (uint32_t)__shfl((int)p00, L0) & pmsk;
            aP0.u[1] = (uint32_t)__shfl((int)p01, L0) & pmsk;
            aP0.u[2] = (uint32_t)__shfl((int)p00, L1) & pmsk;
            aP0.u[3] = (uint32_t)__shfl((int)p01, L1) & pmsk;
            aP1.u[0] = (uint32_t)__shfl((int)p10, L0) & pmsk;
            aP1.u[1] = (uint32_t)__shfl((int)p11, L0) & pmsk;
            aP1.u[2] = (uint32_t)__shfl((int)p10, L1) & pmsk;
            aP1.u[3] = (uint32_t)__shfl((int)p11, L1) & pmsk;

            // transposed updates: accumulate W^T in registers
#pragma unroll
            for (int n = 0; n < 4; ++n) {
                woC[n] = MFMA16(vfr[n], aP0.v, woC[n]);
                wiC[n] = MFMA16(kfr[n], aP1.v, wiC[n]);
            }
            BUILD_WFRAG(wiC, fWi0, fWi1);
            BUILD_WFRAG(woC, fWo0, fWo1);

            if (it == 1 && c + 1 < NCHUNK) {
                if (lo < 4) {
#pragma unroll
                    for (int n = 0; n < 4; ++n)
#pragma unroll
                        for (int r = 0; r < 4; ++r)
                            VT2[nxt][16 * n + 4 * g + r][16 + lo] = f2bf(woC[n][r]);
                }
                STAGE(nxt);
            }
            SYNC();
        }
    }
}

// ---------------------------------------------------------------------------
// launch — all-bf16 dataflow (verified R11), fused weight f2b
// ---------------------------------------------------------------------------
extern "C" void kernel_launch(void* const* d_in, const int* in_sizes, int n_in,
                              void* d_out, int out_size, void* d_ws, size_t ws_size,
                              hipStream_t stream)
{
    const float* hs  = (const float*)d_in[0];
    const float* Wq  = (const float*)d_in[1];
    const float* Wk  = (const float*)d_in[2];
    const float* Wv  = (const float*)d_in[3];
    const float* Wlr = (const float*)d_in[4];
    const float* Wg  = (const float*)d_in[5];
    const float* Wo  = (const float*)d_in[6];
    const float* cq  = (const float*)d_in[7];
    const float* ck  = (const float*)d_in[8];
    const float* cv  = (const float*)d_in[9];
    const float* Wi0 = (const float*)d_in[10];
    const float* Wo0 = (const float*)d_in[11];
    const float* lng = (const float*)d_in[12];
    const float* lnb = (const float*)d_in[13];

    ushort* Qb   = (ushort*)d_ws;
    ushort* Kb   = Qb + (size_t)NROWS * DIM;
    ushort* Vb   = Kb + (size_t)NROWS * DIM;
    ushort* hsb  = Vb + (size_t)NROWS * DIM;
    ushort* Wqb  = hsb + (size_t)NROWS * DIM;
    ushort* Wkb  = Wqb + (size_t)DIM * DIM;
    ushort* Wvb  = Wkb + (size_t)DIM * DIM;
    ushort* Wgb  = Wvb + (size_t)DIM * DIM;
    ushort* Wob  = Wgb + (size_t)DIM * DIM;
    ushort* HALO = Wob + (size_t)DIM * DIM;
    float*  LRb  = (float*)(HALO + (size_t)3 * BATCH * NSEG * 3 * DIM);
    float*  GATE = (float*)d_out;
    ushort* OBUF = hsb;   // hs bf16 dead after projections (stream-ordered)

    dim3 blk(256);

    f2b_kernel<<<2048, blk, 0, stream>>>(hs, hsb, NROWS * DIM / 8);
    f2b5_kernel<<<640, blk, 0, stream>>>(Wq, Wk, Wv, Wg, Wo, Wqb);

    gemm_lds_b16o<<<dim3(8, 128), blk, 0, stream>>>(hsb, Wqb, Qb, 1024);
    gemm_lds_b16o<<<dim3(8, 128), blk, 0, stream>>>(hsb, Wkb, Kb, 1024);
    gemm_lds_b16o<<<dim3(8, 128), blk, 0, stream>>>(hsb, Wvb, Vb, 1024);
    gemm_lds_f32o<<<dim3(8, 128), blk, 0, stream>>>(hsb, Wgb, GATE, 1024);

    lr_kernel<<<NROWS, blk, 0, stream>>>(hs, Wlr, LRb);

    halo_save<<<3 * BATCH * (NSEG - 1) * 3, blk, 0, stream>>>(Qb, Kb, Vb, HALO);
    conv_inplace<<<(3 * BATCH * NH * NSEG) / 4, blk, 0, stream>>>(Qb, Kb, Vb, HALO,
                                                                  cq, ck, cv);

    scan_kernel<<<BATCH * NH, dim3(64), 0, stream>>>(Qb, Kb, Vb, LRb, GATE,
                                                     Wi0, Wo0, lng, lnb, OBUF);

    gemm_lds_f32o<<<dim3(8, 128), blk, 0, stream>>>(OBUF, Wob, (float*)d_out, 1024);
}

// Round 13
// 1729.236 us; speedup vs baseline: 1.0384x; 1.0384x over previous
//
#include <hip/hip_runtime.h>
#include <cstdint>
#include <cstddef>

#define DIM    1024
#define NH     16
#define HD     64
#define CHUNK_ 16
#define SEQ    4096
#define BATCH  4
#define NROWS  (BATCH * SEQ)       // 16384
#define NCHUNK (SEQ / CHUNK_)      // 256
#define SEG    64
#define NSEG   (SEQ / SEG)         // 64

using bf16x8 = __attribute__((ext_vector_type(8))) short;
using f32x4  = __attribute__((ext_vector_type(4))) float;
typedef union { bf16x8 v; uint32_t u[4]; } B8;

#define MFMA16(a, b, c) __builtin_amdgcn_mfma_f32_16x16x32_bf16((a), (b), (c), 0, 0, 0)

__device__ __forceinline__ ushort f2bf(float f) {
    uint32_t u = __float_as_uint(f);
    u += 0x7FFFu + ((u >> 16) & 1u);      // RTNE
    return (ushort)(u >> 16);
}
__device__ __forceinline__ uint32_t pack2(float a, float b) {
    return (uint32_t)f2bf(a) | ((uint32_t)f2bf(b) << 16);
}
__device__ __forceinline__ float b2f(ushort u) {
    return __uint_as_float(((uint32_t)u) << 16);
}
__device__ __forceinline__ float dot4(const float4 a, const float4 b) {
    return a.x*b.x + a.y*b.y + a.z*b.z + a.w*b.w;
}

// DPP row-of-16 rotate reduction (VALU pipe) — verified R10
template <int N>
__device__ __forceinline__ float ror16(float x) {
    return __int_as_float(__builtin_amdgcn_update_dpp(
        0, __float_as_int(x), 0x120 + N, 0xF, 0xF, true));   // ROW_ROR:N
}
__device__ __forceinline__ float dppsum16(float x) {
    x += ror16<1>(x); x += ror16<2>(x);
    x += ror16<4>(x); x += ror16<8>(x);
    return x;
}

// intra-wave memory fence ONLY: orders DS/global ops (cross-lane LDS RAW
// safety via in-wave FIFO retire) while letting register-only VALU/MFMA
// float across phase boundaries for latency hiding. (R13 change: dropped
// wave_barrier + sched_barrier(0) — they pinned ALL instructions.)
#define SYNC() asm volatile("" ::: "memory")

__device__ __forceinline__ void gl_lds16(const void* g, void* l) {
    __builtin_amdgcn_global_load_lds(
        (const __attribute__((address_space(1))) void*)g,
        (__attribute__((address_space(3))) void*)l, 16, 0, 0);
}

// ---------------------------------------------------------------------------
// fp32 -> bf16 converters
// ---------------------------------------------------------------------------
__global__ __launch_bounds__(256)
void f2b_kernel(const float* __restrict__ in, ushort* __restrict__ out, int n8)
{
    int i = blockIdx.x * 256 + threadIdx.x;
    const int stride = gridDim.x * 256;
    for (; i < n8; i += stride) {
        float4 a = *(const float4*)&in[(size_t)i * 8];
        float4 b = *(const float4*)&in[(size_t)i * 8 + 4];
        uint4 u;
        u.x = pack2(a.x, a.y); u.y = pack2(a.z, a.w);
        u.z = pack2(b.x, b.y); u.w = pack2(b.z, b.w);
        *(uint4*)&out[(size_t)i * 8] = u;
    }
}

// all 5 weight matrices in one dispatch (dst contiguous) — verified R12
__global__ __launch_bounds__(256)
void f2b5_kernel(const float* __restrict__ w0, const float* __restrict__ w1,
                 const float* __restrict__ w2, const float* __restrict__ w3,
                 const float* __restrict__ w4, ushort* __restrict__ out)
{
    const int W8 = DIM * DIM / 8;
    const int w  = blockIdx.x >> 7;           // 128 blocks per weight
    const float* src = (w == 0) ? w0 : (w == 1) ? w1 : (w == 2) ? w2
                     : (w == 3) ? w3 : w4;
    ushort* dst = out + (size_t)w * DIM * DIM;
    for (int i = (blockIdx.x & 127) * 256 + threadIdx.x; i < W8; i += 128 * 256) {
        float4 a = *(const float4*)&src[(size_t)i * 8];
        float4 b = *(const float4*)&src[(size_t)i * 8 + 4];
        uint4 u;
        u.x = pack2(a.x, a.y); u.y = pack2(a.z, a.w);
        u.z = pack2(b.x, b.y); u.w = pack2(b.z, b.w);
        *(uint4*)&dst[(size_t)i * 8] = u;
    }
}

// ---------------------------------------------------------------------------
// m97-style bf16 GEMM (NT) — verified R11
// ---------------------------------------------------------------------------
#define GEMM_LDS_BODY(EPILOG)                                                  \
    __shared__ ushort As[128][64];                                             \
    __shared__ ushort Bs[128][64];                                             \
    const int tid  = threadIdx.x, wave = tid >> 6, lane = tid & 63;            \
    const int m0   = blockIdx.y * 128, n0 = blockIdx.x * 128;                  \
    const int lo   = lane & 15, kg = lane >> 4;                                \
    const int wm   = (wave >> 1) * 64, wn = (wave & 1) * 64;                   \
    const int rin  = lane >> 3, sl = lane & 7;                                 \
    const int sb   = 32 * wave;                                                \
    f32x4 acc[4][4];                                                           \
    _Pragma("unroll")                                                          \
    for (int i = 0; i < 4; ++i)                                                \
        _Pragma("unroll")                                                      \
        for (int j = 0; j < 4; ++j) acc[i][j] = (f32x4){0.f, 0.f, 0.f, 0.f};   \
    const int swz = lo & 7;                                                    \
    for (int kt = 0; kt < K; kt += 64) {                                       \
        __syncthreads();                                                       \
        _Pragma("unroll")                                                      \
        for (int i = 0; i < 4; ++i) {                                          \
            const int row = sb + 8 * i + rin;                                  \
            const int gs  = sl ^ (row & 7);                                    \
            gl_lds16(A + (size_t)(m0 + row) * K + kt + gs * 8,                 \
                     &As[sb + 8 * i][0]);                                      \
            gl_lds16(B + (size_t)(n0 + row) * K + kt + gs * 8,                 \
                     &Bs[sb + 8 * i][0]);                                      \
        }                                                                      \
        __syncthreads();                                                       \
        bf16x8 af[2][4], bfr[2][4];                                            \
        _Pragma("unroll")                                                      \
        for (int kk = 0; kk < 2; ++kk)                                         \
            _Pragma("unroll")                                                  \
            for (int m = 0; m < 4; ++m) {                                      \
                const int s = (kk * 4 + kg) ^ swz;                             \
                af[kk][m]  = *(const bf16x8*)&As[wm + m * 16 + lo][s * 8];     \
                bfr[kk][m] = *(const bf16x8*)&Bs[wn + m * 16 + lo][s * 8];     \
            }                                                                  \
        _Pragma("unroll")                                                      \
        for (int kk = 0; kk < 2; ++kk)                                         \
            _Pragma("unroll")                                                  \
            for (int mt = 0; mt < 4; ++mt)                                     \
                _Pragma("unroll")                                              \
                for (int nt = 0; nt < 4; ++nt)                                 \
                    acc[mt][nt] = MFMA16(af[kk][mt], bfr[kk][nt], acc[mt][nt]);\
    }                                                                          \
    const int col = lane & 15, r4 = (lane >> 4) * 4;                           \
    _Pragma("unroll")                                                          \
    for (int mt = 0; mt < 4; ++mt)                                             \
        _Pragma("unroll")                                                      \
        for (int nt = 0; nt < 4; ++nt)                                         \
            _Pragma("unroll")                                                  \
            for (int j = 0; j < 4; ++j) {                                      \
                size_t idx = (size_t)(m0 + wm + mt * 16 + r4 + j) * DIM +      \
                             n0 + wn + nt * 16 + col;                          \
                EPILOG;                                                        \
            }

__global__ __launch_bounds__(256)
void gemm_lds_b16o(const ushort* __restrict__ A, const ushort* __restrict__ B,
                   ushort* __restrict__ C, int K)
{
    GEMM_LDS_BODY(C[idx] = f2bf(acc[mt][nt][j]))
}

__global__ __launch_bounds__(256)
void gemm_lds_f32o(const ushort* __restrict__ A, const ushort* __restrict__ B,
                   float* __restrict__ C, int K)
{
    GEMM_LDS_BODY(C[idx] = acc[mt][nt][j])
}

// ---------------------------------------------------------------------------
// lr kernel (exact fp32)
// ---------------------------------------------------------------------------
__global__ __launch_bounds__(256)
void lr_kernel(const float* __restrict__ hs, const float* __restrict__ Wlr,
               float* __restrict__ LR)
{
    __shared__ float row[DIM];
    const int r = blockIdx.x;
    const int t = threadIdx.x;
    *(float4*)&row[t * 4] = *(const float4*)&hs[(size_t)r * DIM + t * 4];
    __syncthreads();

    const int o = t >> 3;
    const int p = t & 7;
    const float* w = Wlr + (size_t)o * DIM + p * 128;
    const float* x = row + p * 128;
    float acc = 0.f;
#pragma unroll
    for (int i = 0; i < 32; ++i) {
        float4 xv = *(const float4*)(x + i * 4);
        float4 wv = *(const float4*)(w + i * 4);
        acc += dot4(xv, wv);
    }
    acc += __shfl_xor(acc, 1);
    acc += __shfl_xor(acc, 2);
    acc += __shfl_xor(acc, 4);
    if (p == 0) {
        float xx = acc + 0.001f;
        LR[(size_t)r * 32 + o] = (xx > 20.f) ? xx : log1pf(expf(xx));
    }
}

// ---------------------------------------------------------------------------
// halo save (bf16 — verified R11)
// ---------------------------------------------------------------------------
__global__ __launch_bounds__(256)
void halo_save(const ushort* __restrict__ Q, const ushort* __restrict__ K,
               const ushort* __restrict__ V, ushort* __restrict__ HALO)
{
    int idx = blockIdx.x;
    int tn  = idx / (BATCH * (NSEG - 1) * 3);
    int rem = idx - tn * (BATCH * (NSEG - 1) * 3);
    int b   = rem / ((NSEG - 1) * 3);
    int rem2= rem - b * ((NSEG - 1) * 3);
    int s   = rem2 / 3 + 1;
    int j   = rem2 - (s - 1) * 3;

    const ushort* buf = (tn == 0) ? Q : ((tn == 1) ? K : V);
    size_t src = ((size_t)(b * SEQ + s * SEG - 3 + j)) * DIM + threadIdx.x * 4;
    size_t dst = ((size_t)((tn * BATCH + b) * NSEG + s) * 3 + j) * DIM + threadIdx.x * 4;
    *(uint2*)&HALO[dst] = *(const uint2*)&buf[src];
}

// ---------------------------------------------------------------------------
// conv in-place (bf16 buffers, fp32 math — verified R11)
// ---------------------------------------------------------------------------
__global__ __launch_bounds__(256)
void conv_inplace(ushort* __restrict__ Q, ushort* __restrict__ K,
                  ushort* __restrict__ V, const ushort* __restrict__ HALO,
                  const float* __restrict__ cq, const float* __restrict__ ck,
                  const float* __restrict__ cv)
{
    const int wid  = (blockIdx.x << 2) + (threadIdx.x >> 6);
    const int lane = threadIdx.x & 63;
    const int tn   = wid >> 12;
    const int rem  = wid & 4095;
    const int b    = rem >> 10;
    const int rem2 = rem & 1023;
    const int h    = rem2 >> 6;
    const int s    = rem2 & 63;
    const int c    = (h << 6) + lane;

    ushort* buf = (tn == 0) ? Q : ((tn == 1) ? K : V);
    const float* cw = (tn == 0) ? cq : ((tn == 1) ? ck : cv);
    float4 w4 = *(const float4*)(cw + (c << 2));

    float xm3 = 0.f, xm2 = 0.f, xm1 = 0.f;
    if (s > 0) {
        size_t hb = ((size_t)((tn * BATCH + b) * NSEG + s) * 3) * DIM + c;
        xm3 = b2f(HALO[hb]);
        xm2 = b2f(HALO[hb + DIM]);
        xm1 = b2f(HALO[hb + 2 * DIM]);
    }

    size_t base = ((size_t)(b * SEQ + s * SEG)) * DIM + c;
    float x_next = b2f(buf[base]);
#pragma unroll 4
    for (int i = 0; i < SEG; ++i) {
        float x = x_next;
        if (i < SEG - 1) x_next = b2f(buf[base + (size_t)(i + 1) * DIM]);
        float y = xm3 * w4.x + xm2 * w4.y + xm1 * w4.z + x * w4.w + x;
        y = y / (1.f + __expf(-y));
        if (tn < 2) {
            float n2 = y * y;
#pragma unroll
            for (int m = 1; m < 64; m <<= 1) n2 += __shfl_xor(n2, m);
            y *= rsqrtf(n2);
        }
        buf[base + (size_t)i * DIM] = f2bf(y);
        xm3 = xm2; xm2 = xm1; xm1 = x;
    }
}

// ---------------------------------------------------------------------------
// MFMA scan — R11-verified structure (best measured: 1134 µs), with the
// lightened memory-only SYNC. One wave per (b,h) chain, 64 blocks,
// double-buffered chunk tiles, DPP LN, transposed inner scores, P via shfl.
// ---------------------------------------------------------------------------
__global__ __launch_bounds__(64)
void scan_kernel(const ushort* QP, const ushort* __restrict__ KP,
                 const ushort* __restrict__ VP, const float* __restrict__ LRb,
                 const float* __restrict__ GATE,
                 const float* __restrict__ Wi0, const float* __restrict__ Wo0,
                 const float* __restrict__ lng, const float* __restrict__ lnb,
                 ushort* OB)
{
    const int bh = blockIdx.x, b = bh >> 4, h = bh & 15;
    const int t  = threadIdx.x, lo = t & 15, g = t >> 4;

    __shared__ ushort KA2[2][16][72], QA2[2][16][72], VA2[2][16][72];
    __shared__ float  sG2[2][16][68];
    __shared__ ushort KT2[2][64][24];
    __shared__ ushort VT2[2][64][40];            // [d][V^T | Wo^T(16-19) | 0]
    __shared__ ushort WiA[16][72], WoA[16][72];  // rows 4-15 zero
    __shared__ ushort QKT[16][32], KH[16][32];

    for (int i = t; i < 16 * 72; i += 64) { ((ushort*)WiA)[i] = 0; ((ushort*)WoA)[i] = 0; }
    for (int i = t; i < 2 * 64 * 24; i += 64) ((ushort*)KT2)[i] = 0;
    for (int i = t; i < 2 * 64 * 40; i += 64) ((ushort*)VT2)[i] = 0;
    for (int i = t; i < 16 * 32; i += 64) { ((ushort*)QKT)[i] = 0; ((ushort*)KH)[i] = 0; }

    f32x4 wiC[4], woC[4];
#pragma unroll
    for (int n = 0; n < 4; ++n) { wiC[n] = (f32x4){0,0,0,0}; woC[n] = (f32x4){0,0,0,0}; }
    if (g == 0) {
#pragma unroll
        for (int n = 0; n < 4; ++n)
#pragma unroll
            for (int D = 0; D < 4; ++D) {
                float wi = Wi0[((size_t)D * NH + h) * HD + 16 * n + lo];
                float wo = Wo0[((size_t)D * NH + h) * HD + 16 * n + lo];
                wiC[n][D] = wi; woC[n][D] = wo;
                WiA[D][16 * n + lo] = f2bf(wi);
                WoA[D][16 * n + lo] = f2bf(wo);
                VT2[0][16 * n + lo][16 + D] = f2bf(wo);
            }
    }
    __builtin_amdgcn_wave_barrier();   // one-time init fence (not in hot loop)
    SYNC();

    float lnGr[4], lnBr[4];
#pragma unroll
    for (int n = 0; n < 4; ++n) { lnGr[n] = lng[16 * n + lo]; lnBr[n] = lnb[16 * n + lo]; }

    const int rowb = b * SEQ;
    const ushort* QPh = QP + h * 64;
    const ushort* KPh = KP + h * 64;
    const ushort* VPh = VP + h * 64;
    const float*  GPh = GATE + h * 64;
    ushort*       OBh = OB + h * 64;

    uint2 pq[4], pk[4], pv[4];
    float4 pg[4];
    float plr_q, plr_i, plr_o;

    // prefetch chunk 0
    {
#pragma unroll
        for (int i = 0; i < 4; ++i) {
            size_t go = (size_t)(rowb + i * 4 + g) * DIM + 4 * lo;
            pq[i] = *(const uint2*)&QPh[go];
            pk[i] = *(const uint2*)&KPh[go];
            pv[i] = *(const uint2*)&VPh[go];
            pg[i] = *(const float4*)&GPh[go];
        }
        plr_q = LRb[(size_t)(rowb + lo) * 32 + h * 2 + 1];
        plr_i = LRb[(size_t)rowb * 32 + h * 2];
        plr_o = LRb[(size_t)rowb * 32 + h * 2 + 1];
    }

    auto STAGE = [&](int nb) {
#pragma unroll
        for (int i = 0; i < 4; ++i) {
            const int row = i * 4 + g;
            *(float4*)&sG2[nb][row][4 * lo] = pg[i];
            *(uint2*)&QA2[nb][row][4 * lo] = pq[i];
            *(uint2*)&KA2[nb][row][4 * lo] = pk[i];
            *(uint2*)&VA2[nb][row][4 * lo] = pv[i];
            uint2 uk = pk[i], uv = pv[i];
            KT2[nb][4 * lo + 0][row] = (ushort)(uk.x & 0xFFFF);
            KT2[nb][4 * lo + 1][row] = (ushort)(uk.x >> 16);
            KT2[nb][4 * lo + 2][row] = (ushort)(uk.y & 0xFFFF);
            KT2[nb][4 * lo + 3][row] = (ushort)(uk.y >> 16);
            VT2[nb][4 * lo + 0][row] = (ushort)(uv.x & 0xFFFF);
            VT2[nb][4 * lo + 1][row] = (ushort)(uv.x >> 16);
            VT2[nb][4 * lo + 2][row] = (ushort)(uv.y & 0xFFFF);
            VT2[nb][4 * lo + 3][row] = (ushort)(uv.y >> 16);
        }
    };

    STAGE(0);
    SYNC();

    const f32x4 z4 = (f32x4){0.f, 0.f, 0.f, 0.f};
    const uint32_t pmsk = (g < 2) ? 0xFFFFFFFFu : 0u;   // zero k-slices 16..31
    const int L0 = (lo + 32 * g) & 63, L1 = (L0 + 16) & 63;

    for (int c = 0; c < NCHUNK; ++c) {
        const int rb  = rowb + c * CHUNK_;
        const int cur = c & 1, nxt = cur ^ 1;
        ushort (*KAc)[72] = KA2[cur];
        ushort (*QAc)[72] = QA2[cur];
        ushort (*VAc)[72] = VA2[cur];
        float  (*sGc)[68] = sG2[cur];
        ushort (*KTc)[24] = KT2[cur];
        ushort (*VTc)[40] = VT2[cur];

        const float lr1    = plr_q;
        const float lr_in  = plr_i;
        const float lr_out = plr_o;

        // ---- issue prefetch for chunk c+1 (lands during this chunk) ----
        if (c + 1 < NCHUNK) {
            const int rb2 = rb + CHUNK_;
#pragma unroll
            for (int i = 0; i < 4; ++i) {
                size_t go = (size_t)(rb2 + i * 4 + g) * DIM + 4 * lo;
                pq[i] = *(const uint2*)&QPh[go];
                pk[i] = *(const uint2*)&KPh[go];
                pv[i] = *(const uint2*)&VPh[go];
                pg[i] = *(const float4*)&GPh[go];
            }
            plr_q = LRb[(size_t)(rb2 + lo) * 32 + h * 2 + 1];
            plr_i = LRb[(size_t)rb2 * 32 + h * 2];
            plr_o = LRb[(size_t)rb2 * 32 + h * 2 + 1];
        }

        // ---- phase A: M1/M2 logits^T, softmaxD, M3 qk, bounce write ----
        bf16x8 xWi0 = *(const bf16x8*)&WiA[lo][g * 8];
        bf16x8 xWi1 = *(const bf16x8*)&WiA[lo][g * 8 + 32];
        f32x4 cK = MFMA16(xWi0, *(const bf16x8*)&KAc[lo][g * 8], z4);
        cK = MFMA16(xWi1, *(const bf16x8*)&KAc[lo][g * 8 + 32], cK);
        f32x4 cQ = MFMA16(xWi0, *(const bf16x8*)&QAc[lo][g * 8], z4);
        cQ = MFMA16(xWi1, *(const bf16x8*)&QAc[lo][g * 8 + 32], cQ);

        float mK = fmaxf(fmaxf(cK[0], cK[1]), fmaxf(cK[2], cK[3]));
        float ek0 = __expf(cK[0] - mK), ek1 = __expf(cK[1] - mK);
        float ek2 = __expf(cK[2] - mK), ek3 = __expf(cK[3] - mK);
        float ivk = lr1 / (ek0 + ek1 + ek2 + ek3);
        float kh0 = ek0 * ivk, kh1 = ek1 * ivk, kh2 = ek2 * ivk, kh3 = ek3 * ivk;

        float mQ = fmaxf(fmaxf(cQ[0], cQ[1]), fmaxf(cQ[2], cQ[3]));
        float eq0 = __expf(cQ[0] - mQ), eq1 = __expf(cQ[1] - mQ);
        float eq2 = __expf(cQ[2] - mQ), eq3 = __expf(cQ[3] - mQ);
        float ivq = 1.f / (eq0 + eq1 + eq2 + eq3);
        float qh0 = eq0 * ivq, qh1 = eq1 * ivq, qh2 = eq2 * ivq, qh3 = eq3 * ivq;

        B8 aQh, bKh;
        aQh.u[0] = aQh.u[1] = aQh.u[2] = aQh.u[3] = 0;
        bKh.u[0] = bKh.u[1] = bKh.u[2] = bKh.u[3] = 0;
        if (g == 0) {
            aQh.u[0] = pack2(qh0, qh1); aQh.u[1] = pack2(qh2, qh3);
            bKh.u[0] = pack2(kh0, kh1); bKh.u[1] = pack2(kh2, kh3);
        }
        f32x4 cQK = MFMA16(aQh.v, bKh.v, z4);

#pragma unroll
        for (int r = 0; r < 4; ++r) {
            const int q = 4 * g + r;
            QKT[q][lo] = (lo <= q) ? f2bf(cQK[r]) : (ushort)0;
        }
        if (g == 0) {
            QKT[lo][16] = f2bf(qh0); QKT[lo][17] = f2bf(qh1);
            QKT[lo][18] = f2bf(qh2); QKT[lo][19] = f2bf(qh3);
            KH[0][lo] = f2bf(kh0); KH[1][lo] = f2bf(kh1);
            KH[2][lo] = f2bf(kh2); KH[3][lo] = f2bf(kh3);
        }
        SYNC();

        // ---- phase B: M4 o, LN (DPP) + gate + bf16 store, update1 ----
        bf16x8 aO = *(const bf16x8*)&QKT[lo][g * 8];
        f32x4 oA[4];
#pragma unroll
        for (int n = 0; n < 4; ++n)
            oA[n] = MFMA16(aO, *(const bf16x8*)&VTc[16 * n + lo][g * 8], z4);
#pragma unroll
        for (int r = 0; r < 4; ++r) {
            float s1 = oA[0][r] + oA[1][r] + oA[2][r] + oA[3][r];
            float s2 = oA[0][r] * oA[0][r] + oA[1][r] * oA[1][r] +
                       oA[2][r] * oA[2][r] + oA[3][r] * oA[3][r];
            s1 = dppsum16(s1); s2 = dppsum16(s2);
            float mu = s1 * (1.f / 64.f);
            float rstd = rsqrtf(s2 * (1.f / 64.f) - mu * mu + 1e-5f);
            const int q = 4 * g + r;
#pragma unroll
            for (int n = 0; n < 4; ++n) {
                float val = (oA[n][r] - mu) * rstd * lnGr[n] + lnBr[n];
                val *= sGc[q][16 * n + lo];
                OBh[(size_t)(rb + q) * DIM + 16 * n + lo] = f2bf(val);
            }
        }
        {
            bf16x8 aKH = *(const bf16x8*)&KH[lo][g * 8];
#pragma unroll
            for (int n = 0; n < 4; ++n)
                woC[n] = MFMA16(aKH, *(const bf16x8*)&VTc[16 * n + lo][g * 8], woC[n]);
        }
        if (g == 0) {
#pragma unroll
            for (int n = 0; n < 4; ++n)
#pragma unroll
                for (int D = 0; D < 4; ++D)
                    WoA[D][16 * n + lo] = f2bf(woC[n][D]);
        }
        SYNC();

        // ---- phases C,D: inner TTT (transposed scores, P via shfl) ----
#pragma unroll
        for (int it = 0; it < 2; ++it) {
            bf16x8 aK0 = *(const bf16x8*)&KAc[lo][g * 8];
            bf16x8 aK1 = *(const bf16x8*)&KAc[lo][g * 8 + 32];
            bf16x8 aV0 = *(const bf16x8*)&VAc[lo][g * 8];
            bf16x8 aV1 = *(const bf16x8*)&VAc[lo][g * 8 + 32];
            bf16x8 bWi0 = *(const bf16x8*)&WiA[lo][g * 8];
            bf16x8 bWi1 = *(const bf16x8*)&WiA[lo][g * 8 + 32];
            bf16x8 bWo0 = *(const bf16x8*)&WoA[lo][g * 8];
            bf16x8 bWo1 = *(const bf16x8*)&WoA[lo][g * 8 + 32];
            f32x4 s0T = MFMA16(aK0, bWi0, z4);
            s0T = MFMA16(aK1, bWi1, s0T);
            f32x4 s1T = MFMA16(aV0, bWo0, z4);
            s1T = MFMA16(aV1, bWo1, s1T);

            float x0[4], x1[4];
#pragma unroll
            for (int r = 0; r < 4; ++r) {
                x0[r] = s0T[r] * 0.125f;
                x1[r] = s1T[r] * 0.125f;
            }
            float m0 = fmaxf(fmaxf(x0[0], x0[1]), fmaxf(x0[2], x0[3]));
            float m1 = fmaxf(fmaxf(x1[0], x1[1]), fmaxf(x1[2], x1[3]));
            m0 = fmaxf(m0, __shfl_xor(m0, 16)); m0 = fmaxf(m0, __shfl_xor(m0, 32));
            m1 = fmaxf(m1, __shfl_xor(m1, 16)); m1 = fmaxf(m1, __shfl_xor(m1, 32));
            float e0[4], e1[4];
#pragma unroll
            for (int r = 0; r < 4; ++r) {
                e0[r] = __expf(x0[r] - m0);
                e1[r] = __expf(x1[r] - m1);
            }
            float su0 = e0[0] + e0[1] + e0[2] + e0[3];
            float su1 = e1[0] + e1[1] + e1[2] + e1[3];
            su0 += __shfl_xor(su0, 16); su0 += __shfl_xor(su0, 32);
            su1 += __shfl_xor(su1, 16); su1 += __shfl_xor(su1, 32);
            const float w0 = lr_out / su0;
            const float w1 = lr_in / su1;

            uint32_t p00 = pack2(e0[0] * w0, e0[1] * w0);
            uint32_t p01 = pack2(e0[2] * w0, e0[3] * w0);
            uint32_t p10 = pack2(e1[0] * w1, e1[1] * w1);
            uint32_t p11 = pack2(e1[2] * w1, e1[3] * w1);
            B8 aP0, aP1;
            aP0.u[0] = (uint32_t)__shfl((int)p00, L0) & pmsk;
            aP0.u[1] = (uint32_t)__shfl((int)p01, L0) & pmsk;
            aP0.u[2] = (uint32_t)__shfl((int)p00, L1) & pmsk;
            aP0.u[3] = (uint32_t)__shfl((int)p01, L1) & pmsk;
            aP1.u[0] = (uint32_t)__shfl((int)p10, L0) & pmsk;
            aP1.u[1] = (uint32_t)__shfl((int)p11, L0) & pmsk;
            aP1.u[2] = (uint32_t)__shfl((int)p10, L1) & pmsk;
            aP1.u[3] = (uint32_t)__shfl((int)p11, L1) & pmsk;

#pragma unroll
            for (int n = 0; n < 4; ++n) {
                woC[n] = MFMA16(aP0.v, *(const bf16x8*)&VTc[16 * n + lo][g * 8], woC[n]);
                wiC[n] = MFMA16(aP1.v, *(const bf16x8*)&KTc[16 * n + lo][g * 8], wiC[n]);
            }

            // stage next chunk's tiles into the other buffer (it==1 only)
            if (it == 1 && c + 1 < NCHUNK) STAGE(nxt);

            if (g == 0) {
#pragma unroll
                for (int n = 0; n < 4; ++n)
#pragma unroll
                    for (int D = 0; D < 4; ++D) {
                        WiA[D][16 * n + lo] = f2bf(wiC[n][D]);
                        WoA[D][16 * n + lo] = f2bf(woC[n][D]);
                        if (it == 1) VT2[nxt][16 * n + lo][16 + D] = f2bf(woC[n][D]);
                    }
            }
            SYNC();
        }
    }
}

// ---------------------------------------------------------------------------
// launch — all-bf16 dataflow (verified R11), fused weight f2b (verified R12)
// ---------------------------------------------------------------------------
extern "C" void kernel_launch(void* const* d_in, const int* in_sizes, int n_in,
                              void* d_out, int out_size, void* d_ws, size_t ws_size,
                              hipStream_t stream)
{
    const float* hs  = (const float*)d_in[0];
    const float* Wq  = (const float*)d_in[1];
    const float* Wk  = (const float*)d_in[2];
    const float* Wv  = (const float*)d_in[3];
    const float* Wlr = (const float*)d_in[4];
    const float* Wg  = (const float*)d_in[5];
    const float* Wo  = (const float*)d_in[6];
    const float* cq  = (const float*)d_in[7];
    const float* ck  = (const float*)d_in[8];
    const float* cv  = (const float*)d_in[9];
    const float* Wi0 = (const float*)d_in[10];
    const float* Wo0 = (const float*)d_in[11];
    const float* lng = (const float*)d_in[12];
    const float* lnb = (const float*)d_in[13];

    ushort* Qb   = (ushort*)d_ws;
    ushort* Kb   = Qb + (size_t)NROWS * DIM;
    ushort* Vb   = Kb + (size_t)NROWS * DIM;
    ushort* hsb  = Vb + (size_t)NROWS * DIM;
    ushort* Wqb  = hsb + (size_t)NROWS * DIM;
    ushort* Wkb  = Wqb + (size_t)DIM * DIM;
    ushort* Wvb  = Wkb + (size_t)DIM * DIM;
    ushort* Wgb  = Wvb + (size_t)DIM * DIM;
    ushort* Wob  = Wgb + (size_t)DIM * DIM;
    ushort* HALO = Wob + (size_t)DIM * DIM;
    float*  LRb  = (float*)(HALO + (size_t)3 * BATCH * NSEG * 3 * DIM);
    float*  GATE = (float*)d_out;
    ushort* OBUF = hsb;   // hs bf16 dead after projections (stream-ordered)

    dim3 blk(256);

    f2b_kernel<<<2048, blk, 0, stream>>>(hs, hsb, NROWS * DIM / 8);
    f2b5_kernel<<<640, blk, 0, stream>>>(Wq, Wk, Wv, Wg, Wo, Wqb);

    gemm_lds_b16o<<<dim3(8, 128), blk, 0, stream>>>(hsb, Wqb, Qb, 1024);
    gemm_lds_b16o<<<dim3(8, 128), blk, 0, stream>>>(hsb, Wkb, Kb, 1024);
    gemm_lds_b16o<<<dim3(8, 128), blk, 0, stream>>>(hsb, Wvb, Vb, 1024);
    gemm_lds_f32o<<<dim3(8, 128), blk, 0, stream>>>(hsb, Wgb, GATE, 1024);

    lr_kernel<<<NROWS, blk, 0, stream>>>(hs, Wlr, LRb);

    halo_save<<<3 * BATCH * (NSEG - 1) * 3, blk, 0, stream>>>(Qb, Kb, Vb, HALO);
    conv_inplace<<<(3 * BATCH * NH * NSEG) / 4, blk, 0, stream>>>(Qb, Kb, Vb, HALO,
                                                                  cq, ck, cv);

    scan_kernel<<<BATCH * NH, dim3(64), 0, stream>>>(Qb, Kb, Vb, LRb, GATE,
                                                     Wi0, Wo0, lng, lnb, OBUF);

    gemm_lds_f32o<<<dim3(8, 128), blk, 0, stream>>>(OBUF, Wob, (float*)d_out, 1024);
}